// Round 4
// baseline (461.171 us; speedup 1.0000x reference)
//
#include <hip/hip_runtime.h>
#include <math.h>

#define LN_EPS_ 1e-5f
#define INV_SQRT_DHEAD 0.17677669529663687f  // 1/sqrt(32)

// B=4, A=16, N=8, L=512, DE=256, DH=64, H=8, DHEAD=32, NL=4096

__device__ __forceinline__ float waveReduceSum(float v) {
    #pragma unroll
    for (int m = 32; m > 0; m >>= 1) v += __shfl_xor(v, m, 64);
    return v;
}
__device__ __forceinline__ float waveReduceMax(float v) {
    #pragma unroll
    for (int m = 32; m > 0; m >>= 1) v = fmaxf(v, __shfl_xor(v, m, 64));
    return v;
}

// ---------------------------------------------------------------------------
// Kernel 1: per (b,a): q = LN(curr_rho) @ Wq.T ; qk[h,e] = sum_dh q[h*32+dh]*Wk[h*32+dh,e]
// g[b,a,h,e] = ln_k_w[e]*qk ; s0 = sum_e g ; s2 = sum_e ln_k_b[e]*qk
// ---------------------------------------------------------------------------
__global__ __launch_bounds__(256) void k_prep(
    const float* __restrict__ curr_rho, const float* __restrict__ Wq,
    const float* __restrict__ Wk, const float* __restrict__ lnqw,
    const float* __restrict__ lnqb, const float* __restrict__ lnkw,
    const float* __restrict__ lnkb,
    float* __restrict__ g, float* __restrict__ s0, float* __restrict__ s2)
{
    __shared__ float xs[256];
    __shared__ float qs[256];
    __shared__ float red[8];
    const int t = threadIdx.x;
    const int w = t >> 6;
    const int ba = blockIdx.x;  // b*16+a
    const float x = curr_rho[(size_t)ba * 256 + t];

    float sm = waveReduceSum(x);
    if ((t & 63) == 0) red[w] = sm;
    __syncthreads();
    const float mu = (red[0] + red[1] + red[2] + red[3]) * (1.0f / 256.0f);
    __syncthreads();
    const float dx = x - mu;
    float sq = waveReduceSum(dx * dx);
    if ((t & 63) == 0) red[w] = sq;
    __syncthreads();
    const float var = (red[0] + red[1] + red[2] + red[3]) * (1.0f / 256.0f);
    const float rstd = 1.0f / sqrtf(var + LN_EPS_);
    __syncthreads();
    xs[t] = dx * rstd * lnqw[t] + lnqb[t];
    __syncthreads();

    // q[t] = dot(xs, Wq[t,:])
    {
        const float4* wq4 = (const float4*)(Wq + (size_t)t * 256);
        float acc = 0.f;
        #pragma unroll 8
        for (int e4 = 0; e4 < 64; ++e4) {
            float4 wv = wq4[e4];
            acc += xs[e4*4+0]*wv.x + xs[e4*4+1]*wv.y + xs[e4*4+2]*wv.z + xs[e4*4+3]*wv.w;
        }
        qs[t] = acc;
    }
    __syncthreads();

    for (int h = 0; h < 8; ++h) {
        float qk = 0.f;
        #pragma unroll 8
        for (int dh = 0; dh < 32; ++dh)
            qk += qs[h*32+dh] * Wk[(size_t)(h*32+dh)*256 + t];
        const float gv = lnkw[t] * qk;
        const float b2 = lnkb[t] * qk;
        g[((size_t)ba * 8 + h) * 256 + t] = gv;
        float sg = waveReduceSum(gv);
        float sb = waveReduceSum(b2);
        if ((t & 63) == 0) { red[w] = sg; red[4 + w] = sb; }
        __syncthreads();
        if (t == 0) {
            s0[ba*8+h] = red[0] + red[1] + red[2] + red[3];
            s2[ba*8+h] = red[4] + red[5] + red[6] + red[7];
        }
        __syncthreads();
    }
}

// ---------------------------------------------------------------------------
// Kernel 2: vals_tan0 = logmap0(demo_hyp)  (rows of 64; one wave per row)
// ---------------------------------------------------------------------------
__global__ __launch_bounds__(256) void k_vals(
    const float* __restrict__ demo_hyp, float* __restrict__ vals)
{
    const int t = threadIdx.x;
    const size_t idx = (size_t)blockIdx.x * 256 + t;
    const float x = demo_hyp[idx];
    const float ss = waveReduceSum(x * x);
    const float nrm = sqrtf(ss);
    const float n = fmaxf(nrm, 1e-15f);
    const float u = fminf(n, 1.0f - 1e-5f);
    const float f = atanhf(u) / n;
    vals[idx] = x * f;
}

// ---------------------------------------------------------------------------
// Kernel 3 (the streamer): scores[b,h,a,n,l] = (rstd*(S1 - mu*s0) + s2)/sqrt(32)
// Geometry: 16 lanes/row, 16 floats/lane (element k*64 + c*4 .. +3 -> dense
// 256B per 16-lane group per instr). 4 rows/wave, 16 rows/pass, 8 passes.
// Reduce-scatter butterfly: 10 shfl (m=8) + fold + 15 shfl (m=4,2,1) + 2 = 27
// cross-lane ops per pass (vs 50 full butterfly).
// ---------------------------------------------------------------------------
__global__ __launch_bounds__(256, 2) void k_scores(
    const float* __restrict__ demo_rho, const int* __restrict__ demo_mask,
    const float* __restrict__ g, const float* __restrict__ s0,
    const float* __restrict__ s2, float* __restrict__ attn)
{
    __shared__ float sbuf[8][132];
    const int t = threadIdx.x;
    const int gid = blockIdx.x;
    const int lc = gid & 3;
    const int n  = (gid >> 2) & 7;
    const int a  = (gid >> 5) & 15;
    const int b  = gid >> 9;
    const int lane = t & 63;
    const int wv   = t >> 6;        // wave 0..3
    const int c    = lane & 15;     // position within 16-lane row group
    const int rowg = lane >> 4;     // row group within wave (0..3)

    // g fragments -> registers: gr[h][k] = g[(ba*8+h)*256 + c*4 + k*64]
    float4 gr[8][4];
    {
        const float* gb = g + ((size_t)(b*16 + a) * 8) * 256 + c * 4;
        #pragma unroll
        for (int h = 0; h < 8; ++h)
            #pragma unroll
            for (int k = 0; k < 4; ++k)
                gr[h][k] = *(const float4*)(gb + h * 256 + k * 64);
    }
    // per-lane h assignment: consumer lanes c in {0..4} -> h=c, {8,9,10} -> h=c-3
    const bool active = (c < 5) || (c >= 8 && c < 11);
    const int  h_eff  = (c < 8) ? ((c < 5) ? c : 0) : ((c < 11) ? c - 3 : 0);
    const float s0v = s0[(b*16 + a) * 8 + h_eff];
    const float s2v = s2[(b*16 + a) * 8 + h_eff];
    const int* mrow = demo_mask + (b*8 + n) * 512 + lc * 128;

    const float* xbase = demo_rho +
        ((size_t)((b*8 + n) * 512 + lc * 128) * 16 + a) * 256 + c * 4;

    // prefetch pass 0
    float4 xk[4];
    {
        const float* xp = xbase + (size_t)(wv * 4 + rowg) * 4096;
        #pragma unroll
        for (int k = 0; k < 4; ++k) xk[k] = *(const float4*)(xp + k * 64);
    }

    for (int p = 0; p < 8; ++p) {
        const int row = p * 16 + wv * 4 + rowg;
        // prefetch next pass
        float4 xn[4];
        if (p < 7) {
            const float* xp = xbase + (size_t)(row + 16) * 4096;
            #pragma unroll
            for (int k = 0; k < 4; ++k) xn[k] = *(const float4*)(xp + k * 64);
        }

        float v[10];
        #pragma unroll
        for (int h = 0; h < 8; ++h) {
            float acc = 0.f;
            #pragma unroll
            for (int k = 0; k < 4; ++k) {
                acc += xk[k].x * gr[h][k].x + xk[k].y * gr[h][k].y
                     + xk[k].z * gr[h][k].z + xk[k].w * gr[h][k].w;
            }
            v[h] = acc;
        }
        {
            float sm = 0.f, sq = 0.f;
            #pragma unroll
            for (int k = 0; k < 4; ++k) {
                sm += xk[k].x + xk[k].y + xk[k].z + xk[k].w;
                sq += xk[k].x*xk[k].x + xk[k].y*xk[k].y
                    + xk[k].z*xk[k].z + xk[k].w*xk[k].w;
            }
            v[8] = sm; v[9] = sq;
        }

        // stage m=8: full exchange of all 10
        #pragma unroll
        for (int i = 0; i < 10; ++i) v[i] += __shfl_xor(v[i], 8, 16);
        // fold: low half keeps v[0..4], high half v[5..9]
        const bool hi = (c & 8);
        float w5[5];
        #pragma unroll
        for (int j = 0; j < 5; ++j) w5[j] = hi ? v[5 + j] : v[j];
        // stages m=4,2,1 on 5 values
        #pragma unroll
        for (int m = 4; m > 0; m >>= 1)
            #pragma unroll
            for (int j = 0; j < 5; ++j) w5[j] += __shfl_xor(w5[j], m, 16);
        // stats: on high half w5[3]=sum, w5[4]=sumsq; broadcast to low
        const float t3 = __shfl_xor(w5[3], 8, 16);
        const float t4 = __shfl_xor(w5[4], 8, 16);
        const float sumv = hi ? w5[3] : t3;
        const float sqv  = hi ? w5[4] : t4;

        if (active) {
            // select this lane's dot: c(0..4)->w5[c]; c(8,9,10)->w5[c-8]
            float sel = w5[0];
            sel = ((c & 7) == 1) ? w5[1] : sel;
            sel = ((c & 7) == 2) ? w5[2] : sel;
            sel = (c == 3) ? w5[3] : sel;
            sel = (c == 4) ? w5[4] : sel;
            const float mu   = sumv * (1.0f / 256.0f);
            const float var  = sqv * (1.0f / 256.0f) - mu * mu;
            const float rstd = 1.0f / sqrtf(var + LN_EPS_);
            float sc = (rstd * (sel - mu * s0v) + s2v) * INV_SQRT_DHEAD;
            if (mrow[row] == 0) sc = -INFINITY;
            sbuf[h_eff][row] = sc;
        }

        #pragma unroll
        for (int k = 0; k < 4; ++k) xk[k] = xn[k];
    }
    __syncthreads();
    // coalesced write of the 8x128 score tile
    {
        const int h = t >> 5;
        const int c32 = t & 31;
        const float* rowp = &sbuf[h][0];
        float4 vout = *(const float4*)(rowp + c32 * 4);
        const size_t off = (size_t)((b*8 + h) * 16 + a) * 4096 + n * 512 + lc * 128 + c32 * 4;
        *(float4*)(attn + off) = vout;
    }
}

// ---------------------------------------------------------------------------
// Kernel 4: softmax over 4096 per (b,h,a) row (2 rows/block) + m_h = attn @ vals
// Dot phase: thread = (x-chunk ch=t>>4, d-quad d4=t&15); float4 vals loads.
// ---------------------------------------------------------------------------
__global__ __launch_bounds__(256) void k_softmax_mh(
    float* __restrict__ attn, const float* __restrict__ vals,
    float* __restrict__ mh)
{
    __shared__ float p0[4096];
    __shared__ float p1[4096];
    __shared__ float red[4];
    __shared__ float wpart[4 * 2 * 64];   // [wave][row][d]
    const int t = threadIdx.x;
    const int w = t >> 6;
    const int row0 = blockIdx.x * 2;
    const int b = row0 >> 7;

    for (int rr = 0; rr < 2; ++rr) {
        const int row = row0 + rr;
        float* dst = attn + (size_t)row * 4096;
        float* pl = rr ? p1 : p0;
        float lmax = -INFINITY;
        float4 v4[4];
        #pragma unroll
        for (int k = 0; k < 4; ++k) {
            float4 vv = ((const float4*)dst)[k * 256 + t];
            v4[k] = vv;
            lmax = fmaxf(lmax, fmaxf(fmaxf(vv.x, vv.y), fmaxf(vv.z, vv.w)));
        }
        lmax = waveReduceMax(lmax);
        if ((t & 63) == 0) red[w] = lmax;
        __syncthreads();
        const float mx = fmaxf(fmaxf(red[0], red[1]), fmaxf(red[2], red[3]));
        __syncthreads();
        float lsum = 0.f;
        #pragma unroll
        for (int k = 0; k < 4; ++k) {
            float4 vv = v4[k];
            vv.x = __expf(vv.x - mx); vv.y = __expf(vv.y - mx);
            vv.z = __expf(vv.z - mx); vv.w = __expf(vv.w - mx);
            v4[k] = vv;
            lsum += vv.x + vv.y + vv.z + vv.w;
        }
        lsum = waveReduceSum(lsum);
        if ((t & 63) == 0) red[w] = lsum;
        __syncthreads();
        const float inv = 1.0f / (red[0] + red[1] + red[2] + red[3]);
        __syncthreads();
        #pragma unroll
        for (int k = 0; k < 4; ++k) {
            float4 vv = v4[k];
            vv.x *= inv; vv.y *= inv; vv.z *= inv; vv.w *= inv;
            ((float4*)pl)[k * 256 + t] = vv;
            ((float4*)dst)[k * 256 + t] = vv;
        }
    }
    __syncthreads();

    // m_h dot: ch = t>>4 (16 x-chunks of 256), d4 = t&15 (d quad)
    const int ch = t >> 4, d4 = t & 15;
    const float* vb = vals + (size_t)b * 4096 * 64 + d4 * 4;
    float4 a0 = {0,0,0,0}, a1 = {0,0,0,0};
    const int x0 = ch * 256;
    #pragma unroll 4
    for (int x = x0; x < x0 + 256; ++x) {
        const float4 vv = *(const float4*)(vb + (size_t)x * 64);
        const float q0 = p0[x], q1 = p1[x];
        a0.x += q0 * vv.x; a0.y += q0 * vv.y; a0.z += q0 * vv.z; a0.w += q0 * vv.w;
        a1.x += q1 * vv.x; a1.y += q1 * vv.y; a1.z += q1 * vv.z; a1.w += q1 * vv.w;
    }
    // reduce across the 4 in-wave chunk groups (lane bits 4,5)
    #pragma unroll
    for (int m = 16; m <= 32; m <<= 1) {
        a0.x += __shfl_xor(a0.x, m, 64); a0.y += __shfl_xor(a0.y, m, 64);
        a0.z += __shfl_xor(a0.z, m, 64); a0.w += __shfl_xor(a0.w, m, 64);
        a1.x += __shfl_xor(a1.x, m, 64); a1.y += __shfl_xor(a1.y, m, 64);
        a1.z += __shfl_xor(a1.z, m, 64); a1.w += __shfl_xor(a1.w, m, 64);
    }
    if ((t & 63) < 16) {
        float* wp0 = wpart + (w * 2 + 0) * 64 + d4 * 4;
        float* wp1 = wpart + (w * 2 + 1) * 64 + d4 * 4;
        wp0[0] = a0.x; wp0[1] = a0.y; wp0[2] = a0.z; wp0[3] = a0.w;
        wp1[0] = a1.x; wp1[1] = a1.y; wp1[2] = a1.z; wp1[3] = a1.w;
    }
    __syncthreads();
    if (t < 128) {
        const int rr = t >> 6, d = t & 63;
        const float m = wpart[(0 * 2 + rr) * 64 + d] + wpart[(1 * 2 + rr) * 64 + d]
                      + wpart[(2 * 2 + rr) * 64 + d] + wpart[(3 * 2 + rr) * 64 + d];
        mh[(size_t)(row0 + rr) * 64 + d] = m;
    }
}

// ---------------------------------------------------------------------------
// Kernel 5: hyperbolic epilogue -> curr_hyp[b][64]; one wave per a (1024 thr)
// ---------------------------------------------------------------------------
__global__ __launch_bounds__(1024) void k_final(
    const float* __restrict__ mh, float* __restrict__ out)
{
    __shared__ float contrib[16][64];
    const int t = threadIdx.x;
    const int a = t >> 6, d = t & 63;
    const int b = blockIdx.x;
    float accY = 0.f;
    #pragma unroll
    for (int h = 0; h < 8; ++h) {
        const float m = mh[(size_t)((b*8 + h) * 16 + a) * 64 + d];
        const float ss = waveReduceSum(m * m);
        const float nm = sqrtf(ss);
        const float n1 = fmaxf(nm, 1e-15f);
        const float t1 = tanhf(n1);
        const float e  = t1 * m / n1;
        const float ne = t1 * nm / n1;
        const float n2 = fmaxf(ne, 1e-15f);
        const float u  = fminf(n2, 1.0f - 1e-5f);
        accY += atanhf(u) * e / n2;
    }
    const float ym = accY * 0.125f;
    const float ssy = waveReduceSum(ym * ym);
    const float nmy = sqrtf(ssy);
    const float n3 = fmaxf(nmy, 1e-15f);
    const float t3 = tanhf(n3);
    const float chv = t3 * ym / n3;
    const float nch = t3 * nmy / n3;
    const float nrm = fmaxf(nch, 1e-6f);
    const float sc = fminf((1.0f - 1e-5f) / nrm, 1.0f);
    contrib[a][d] = chv * sc;
    __syncthreads();
    if (t < 64) {
        float s = 0.f;
        #pragma unroll
        for (int a2 = 0; a2 < 16; ++a2) s += contrib[a2][t];
        out[b * 64 + t] = s * (1.0f / 16.0f);
    }
}

// ---------------------------------------------------------------------------
extern "C" void kernel_launch(void* const* d_in, const int* in_sizes, int n_in,
                              void* d_out, int out_size, void* d_ws, size_t ws_size,
                              hipStream_t stream) {
    const float* curr_rho  = (const float*)d_in[0];
    const float* demo_rho  = (const float*)d_in[1];
    const float* demo_hyp  = (const float*)d_in[2];
    const int*   demo_mask = (const int*)d_in[3];
    const float* Wq   = (const float*)d_in[4];
    const float* Wk   = (const float*)d_in[5];
    const float* lnqw = (const float*)d_in[6];
    const float* lnqb = (const float*)d_in[7];
    const float* lnkw = (const float*)d_in[8];
    const float* lnkb = (const float*)d_in[9];

    float* out  = (float*)d_out;
    float* attn = out + 256;                 // curr_hyp first (B*DH=256), then attn

    float* ws   = (float*)d_ws;
    float* g    = ws;                        // 131072 floats
    float* s0   = ws + 131072;               // 512
    float* s2   = ws + 131584;               // 512
    float* vals = ws + 132096;               // 1048576
    float* mh   = ws + 1180672;              // 32768

    hipLaunchKernelGGL(k_prep, dim3(64), dim3(256), 0, stream,
                       curr_rho, Wq, Wk, lnqw, lnqb, lnkw, lnkb, g, s0, s2);
    hipLaunchKernelGGL(k_vals, dim3(4096), dim3(256), 0, stream, demo_hyp, vals);
    hipLaunchKernelGGL(k_scores, dim3(2048), dim3(256), 0, stream,
                       demo_rho, demo_mask, g, s0, s2, attn);
    hipLaunchKernelGGL(k_softmax_mh, dim3(256), dim3(256), 0, stream, attn, vals, mh);
    hipLaunchKernelGGL(k_final, dim3(4), dim3(1024), 0, stream, mh, out);
}